// Round 1
// baseline (4293.265 us; speedup 1.0000x reference)
//
#include <hip/hip_runtime.h>
#include <hip/hip_bf16.h>
#include <math.h>

// Problem constants
#define BATCH 32
#define TIN   50
#define TOUTS 50
#define HDIM  512
#define VOC   32000
#define NBL   500          // k_logits blocks (64 v-rows each)

// ws layout (float offsets)
#define OFF_HA    0
#define OFF_HB    16384
#define OFF_XC    32768
#define OFF_XCPRE 49152
#define OFF_ATTNX 65536
#define OFF_PM    81920      // 500*32
#define OFF_PS    97920
#define OFF_PA    113920     // int
#define OFF_LSE   129920     // 50*32

// d_out layout (float offsets)
#define OUT_HT    51200000   // B*V*TOUT
#define OUT_ATTN  51216384

typedef unsigned short ushort8 __attribute__((ext_vector_type(8)));

static __device__ __forceinline__ unsigned short f2bf(float x) {
  unsigned int u = __float_as_uint(x);
  unsigned int r = (u + 0x7fffu + ((u >> 16) & 1u)) >> 16;
  return (unsigned short)r;
}
static __device__ __forceinline__ float bf2f(unsigned short s) {
  return __uint_as_float(((unsigned int)s) << 16);
}
static __device__ __forceinline__ float dot4(float4 a, float4 b) {
  return a.x*b.x + a.y*b.y + a.z*b.z + a.w*b.w;
}

// ---------------------------------------------------------------- setup ----
// attn_x[b][h] = sum_t enc[b][t][h]; also zero h0.
__global__ __launch_bounds__(256) void k_setup1(const float* __restrict__ enc,
                                                float* __restrict__ ws) {
  int idx = blockIdx.x * 256 + threadIdx.x;       // 0..16383
  int b = idx >> 9, h = idx & 511;
  const float* p = enc + (size_t)b * TIN * HDIM + h;
  float s = 0.f;
  #pragma unroll 10
  for (int t = 0; t < TIN; ++t) s += p[(size_t)t * HDIM];
  (ws + OFF_ATTNX)[idx] = s;
  (ws + OFF_HA)[idx] = 0.f;
}

// xc_pre[b][i] = b_comb[i] + sum_k attn_x[b][k] * W_comb[i][512+k]
__global__ __launch_bounds__(256) void k_setup2(const float* __restrict__ W_comb,
                                                const float* __restrict__ b_comb,
                                                float* __restrict__ ws) {
  __shared__ float ax[HDIM];
  const int tid = threadIdx.x;
  const int b = blockIdx.x >> 1, half = blockIdx.x & 1;
  if (tid < 128)
    ((float4*)ax)[tid] = ((const float4*)(ws + OFF_ATTNX + b * HDIM))[tid];
  __syncthreads();
  int i = half * 256 + tid;
  float acc = b_comb[i];
  const float4* w4 = (const float4*)W_comb + (size_t)i * 256 + 128; // cols 512..1023
  const float4* a4 = (const float4*)ax;
  #pragma unroll 8
  for (int j = 0; j < 128; ++j) acc += dot4(w4[j], a4[j]);
  (ws + OFF_XCPRE)[b * HDIM + i] = acc;
}

// ------------------------------------------------------------------ k_xc ---
// Reduces previous step's softmax partials (argmax -> tok, writes lse[t-1]),
// then xc[b][i] = relu(xc_pre[b][i] + dot(emb[tok], W_comb[i][0:512])).
__global__ __launch_bounds__(256) void k_xc(const float* __restrict__ emb,
                                            const int* __restrict__ y,
                                            const float* __restrict__ W_comb,
                                            float* __restrict__ ws, int t) {
  __shared__ float sm[256];
  __shared__ int   si[256];
  __shared__ float em[HDIM];
  const int tid = threadIdx.x;
  const int b = blockIdx.x >> 1, half = blockIdx.x & 1;
  const float* pm = ws + OFF_PM;
  const float* ps = ws + OFF_PS;
  const int*   pa = (const int*)(ws + OFF_PA);
  int tok;
  if (t == 0) {
    tok = y[b * TOUTS];                       // y[:,0]
  } else {
    // phase 1: global max + argmax over 500 block-partials (tie -> lower idx)
    float M = pm[tid * 32 + b]; int A = tid;
    if (tid < NBL - 256) {
      float M2 = pm[(tid + 256) * 32 + b];
      if (M2 > M) { M = M2; A = tid + 256; }
    }
    sm[tid] = M; si[tid] = A;
    __syncthreads();
    for (int s = 128; s > 0; s >>= 1) {
      if (tid < s) {
        float M2 = sm[tid + s]; int A2 = si[tid + s];
        if (M2 > sm[tid] || (M2 == sm[tid] && A2 < si[tid])) { sm[tid] = M2; si[tid] = A2; }
      }
      __syncthreads();
    }
    float Mstar = sm[0]; int jstar = si[0];
    __syncthreads();
    // phase 2: logsumexp
    float S = ps[tid * 32 + b] * expf(pm[tid * 32 + b] - Mstar);
    if (tid < NBL - 256)
      S += ps[(tid + 256) * 32 + b] * expf(pm[(tid + 256) * 32 + b] - Mstar);
    sm[tid] = S;
    __syncthreads();
    for (int s = 128; s > 0; s >>= 1) {
      if (tid < s) sm[tid] += sm[tid + s];
      __syncthreads();
    }
    if (tid == 0 && half == 0)
      (ws + OFF_LSE)[(t - 1) * 32 + b] = Mstar + logf(sm[0]);
    tok = pa[jstar * 32 + b];
  }
  // stage emb row
  if (tid < 128)
    ((float4*)em)[tid] = ((const float4*)(emb + (size_t)tok * HDIM))[tid];
  __syncthreads();
  int i = half * 256 + tid;
  float acc = (ws + OFF_XCPRE)[b * HDIM + i];
  const float4* w4 = (const float4*)W_comb + (size_t)i * 256;   // cols 0..511
  const float4* e4 = (const float4*)em;
  #pragma unroll 8
  for (int j = 0; j < 128; ++j) acc += dot4(w4[j], e4[j]);
  (ws + OFF_XC)[b * HDIM + i] = fmaxf(acc, 0.f);
}

// ----------------------------------------------------------------- k_gru ---
// h_new = GRU(xc, h). grid 256 = 4 b-tiles(8) x 64 i-tiles(8).
// threads = 64 (b_l,i_l) pairs x 4 k-quarters (strided f4 for coalescing).
__global__ __launch_bounds__(256) void k_gru(const float* __restrict__ W_ih,
                                             const float* __restrict__ W_hh,
                                             const float* __restrict__ b_ih,
                                             const float* __restrict__ b_hh,
                                             float* __restrict__ ws, int t) {
  __shared__ float xcs[8 * 516];
  __shared__ float hs [8 * 516];
  __shared__ float red[4 * 64 * 6];
  const int tid = threadIdx.x;
  const int btile = blockIdx.x & 3;
  const int itile = blockIdx.x >> 2;            // 0..63
  const int b0 = btile * 8, i0 = itile * 8;
  const float* hb_in  = ws + ((t & 1) ? OFF_HB : OFF_HA);
  float*       hb_out = ws + ((t & 1) ? OFF_HA : OFF_HB);
  const float4* xcg = (const float4*)(ws + OFF_XC);
  const float4* hg  = (const float4*)hb_in;
  #pragma unroll
  for (int q = 0; q < 4; ++q) {
    int pos = q * 256 + tid;                    // f4 idx 0..1023
    int bl = pos >> 7, j = pos & 127;
    ((float4*)xcs)[bl * 129 + j] = xcg[(size_t)(b0 + bl) * 128 + j];
    ((float4*)hs )[bl * 129 + j] = hg [(size_t)(b0 + bl) * 128 + j];
  }
  __syncthreads();
  const int pair = tid >> 2, kh = tid & 3;      // pair 0..63
  const int bl = pair >> 3, il = pair & 7;
  const int i = i0 + il;
  float a0 = 0, a1 = 0, a2 = 0, a3 = 0, a4 = 0, a5 = 0;
  const float4* wi0 = (const float4*)(W_ih + (size_t)(i       ) * HDIM);
  const float4* wi1 = (const float4*)(W_ih + (size_t)(i +  512) * HDIM);
  const float4* wi2 = (const float4*)(W_ih + (size_t)(i + 1024) * HDIM);
  const float4* wh0 = (const float4*)(W_hh + (size_t)(i       ) * HDIM);
  const float4* wh1 = (const float4*)(W_hh + (size_t)(i +  512) * HDIM);
  const float4* wh2 = (const float4*)(W_hh + (size_t)(i + 1024) * HDIM);
  const float4* xv4 = (const float4*)xcs + bl * 129;
  const float4* hv4 = (const float4*)hs  + bl * 129;
  #pragma unroll 4
  for (int j = 0; j < 32; ++j) {
    int f4 = kh + 4 * j;                        // strided -> 64B-coalesced W
    float4 xv = xv4[f4], hv = hv4[f4];
    a0 += dot4(wi0[f4], xv);
    a1 += dot4(wi1[f4], xv);
    a2 += dot4(wi2[f4], xv);
    a3 += dot4(wh0[f4], hv);
    a4 += dot4(wh1[f4], hv);
    a5 += dot4(wh2[f4], hv);
  }
  float* rp = red + (kh * 64 + pair) * 6;
  rp[0] = a0; rp[1] = a1; rp[2] = a2; rp[3] = a3; rp[4] = a4; rp[5] = a5;
  __syncthreads();
  if (tid < 64) {
    const float* r0 = red + (0 * 64 + tid) * 6;
    const float* r1 = red + (1 * 64 + tid) * 6;
    const float* r2 = red + (2 * 64 + tid) * 6;
    const float* r3 = red + (3 * 64 + tid) * 6;
    int bl2 = tid >> 3, il2 = tid & 7;
    int ii = i0 + il2;
    float gir = r0[0] + r1[0] + r2[0] + r3[0] + b_ih[ii];
    float giz = r0[1] + r1[1] + r2[1] + r3[1] + b_ih[ii + 512];
    float gin = r0[2] + r1[2] + r2[2] + r3[2] + b_ih[ii + 1024];
    float ghr = r0[3] + r1[3] + r2[3] + r3[3] + b_hh[ii];
    float ghz = r0[4] + r1[4] + r2[4] + r3[4] + b_hh[ii + 512];
    float ghn = r0[5] + r1[5] + r2[5] + r3[5] + b_hh[ii + 1024];
    float r = 1.f / (1.f + expf(-(gir + ghr)));
    float z = 1.f / (1.f + expf(-(giz + ghz)));
    float n = tanhf(gin + r * ghn);
    float hold = hs[bl2 * 516 + ii];
    hb_out[(b0 + bl2) * HDIM + ii] = (1.f - z) * n + z * hold;
  }
}

// -------------------------------------------------------------- k_logits ---
// logits[b][v] = h_new . W_out[v] + b_out[v], 64 rows/block.
// threads = 32 v-slots (2 rows each) x 8 k-eighths (strided f4).
// Emits: block softmax partials (pm/ps/pa) + bf16 logits into attn region.
__global__ __launch_bounds__(256) void k_logits(const float* __restrict__ W_out,
                                                const float* __restrict__ b_out,
                                                float* __restrict__ ws,
                                                float* __restrict__ out, int t) {
  __shared__ float lds[16384];                  // 64 KiB: h stage, then scratch
  const int tid = threadIdx.x, blk = blockIdx.x;
  const int v0 = blk * 64;
  const float* hb = ws + (((t + 1) & 1) ? OFF_HB : OFF_HA);
  {
    float4* l4 = (float4*)lds;
    const float4* h4 = (const float4*)hb;
    #pragma unroll
    for (int q = 0; q < 16; ++q) l4[q * 256 + tid] = h4[q * 256 + tid];
  }
  __syncthreads();
  const int vl = tid >> 3, kq = tid & 7;
  const int r0 = 2 * vl;
  float acc0[32], acc1[32];
  #pragma unroll
  for (int b2 = 0; b2 < 32; ++b2) { acc0[b2] = 0.f; acc1[b2] = 0.f; }
  const float4* w0 = (const float4*)(W_out + (size_t)(v0 + r0) * HDIM);
  const float4* w1 = w0 + 128;
  const float4* l4 = (const float4*)lds;
  #pragma unroll 1
  for (int ii = 0; ii < 16; ++ii) {
    int f4 = kq + 8 * ii;                       // strided: coalesced W, bank-clean LDS
    float4 wa = w0[f4], wb = w1[f4];
    #pragma unroll
    for (int b2 = 0; b2 < 32; ++b2) {
      float4 hv = l4[b2 * 128 + f4];
      acc0[b2] += dot4(wa, hv);
      acc1[b2] += dot4(wb, hv);
    }
  }
  // reduce the 8 k-partials within the wave
  #pragma unroll
  for (int m = 1; m < 8; m <<= 1) {
    #pragma unroll
    for (int b2 = 0; b2 < 32; ++b2) {
      acc0[b2] += __shfl_xor(acc0[b2], m, 64);
      acc1[b2] += __shfl_xor(acc1[b2], m, 64);
    }
  }
  __syncthreads();                              // all h reads done; reuse lds
  if (kq == 0) {
    float bo0 = b_out[v0 + r0], bo1 = b_out[v0 + r0 + 1];
    #pragma unroll
    for (int b2 = 0; b2 < 32; ++b2) {
      lds[(r0    ) * 33 + b2] = acc0[b2] + bo0;
      lds[(r0 + 1) * 33 + b2] = acc1[b2] + bo1;
    }
  }
  __syncthreads();
  {
    const int b2 = tid >> 3, seg = tid & 7;     // 8 rows per (b,seg)
    float M = -3.4e38f; int A = 0x7fffffff;
    #pragma unroll
    for (int j = 0; j < 8; ++j) {
      float v = lds[(seg * 8 + j) * 33 + b2];
      if (v > M) { M = v; A = v0 + seg * 8 + j; }
    }
    #pragma unroll
    for (int m = 1; m < 8; m <<= 1) {
      float M2 = __shfl_xor(M, m, 64);
      int   A2 = __shfl_xor(A, m, 64);
      if (M2 > M || (M2 == M && A2 < A)) { M = M2; A = A2; }
    }
    float S = 0.f;
    #pragma unroll
    for (int j = 0; j < 8; ++j) S += expf(lds[(seg * 8 + j) * 33 + b2] - M);
    #pragma unroll
    for (int m = 1; m < 8; m <<= 1) S += __shfl_xor(S, m, 64);
    if (seg == 0) {
      (ws + OFF_PM)[blk * 32 + b2] = M;
      (ws + OFF_PS)[blk * 32 + b2] = S;
      ((int*)(ws + OFF_PA))[blk * 32 + b2] = A;
    }
    // store 8 bf16 logits (16B vector, fully coalesced) into attn region
    unsigned short* lb = (unsigned short*)(out + OUT_ATTN);
    ushort8 pk;
    #pragma unroll
    for (int j = 0; j < 8; ++j) pk[j] = f2bf(lds[(seg * 8 + j) * 33 + b2]);
    *((ushort8*)(lb + ((size_t)t * 32 + b2) * VOC + v0 + seg * 8)) = pk;
  }
}

// ---------------------------------------------------------------- k_last ---
// lse for t=49 + hT output copy.
__global__ __launch_bounds__(256) void k_last(float* __restrict__ ws,
                                              float* __restrict__ out) {
  __shared__ float sm[256];
  const int tid = threadIdx.x, blk = blockIdx.x;
  out[OUT_HT + blk * 256 + tid] = (ws + OFF_HA)[blk * 256 + tid]; // h_50 in buf A
  if (blk >= 32) return;
  const int b = blk;
  const float* pm = ws + OFF_PM;
  const float* ps = ws + OFF_PS;
  float M = pm[tid * 32 + b];
  if (tid < NBL - 256) M = fmaxf(M, pm[(tid + 256) * 32 + b]);
  sm[tid] = M; __syncthreads();
  for (int s = 128; s > 0; s >>= 1) { if (tid < s) sm[tid] = fmaxf(sm[tid], sm[tid + s]); __syncthreads(); }
  float Mstar = sm[0]; __syncthreads();
  float S = ps[tid * 32 + b] * expf(pm[tid * 32 + b] - Mstar);
  if (tid < NBL - 256) S += ps[(tid + 256) * 32 + b] * expf(pm[(tid + 256) * 32 + b] - Mstar);
  sm[tid] = S; __syncthreads();
  for (int s = 128; s > 0; s >>= 1) { if (tid < s) sm[tid] += sm[tid + s]; __syncthreads(); }
  if (tid == 0) (ws + OFF_LSE)[49 * 32 + b] = Mstar + logf(sm[0]);
}

// ----------------------------------------------------------- k_transpose ---
// out[b][v][t] = bf16_logits[t][b][v] - lse[t][b].  LDS-tiled, coalesced both ways.
__global__ __launch_bounds__(256) void k_transpose(const float* __restrict__ ws,
                                                   float* __restrict__ out) {
  __shared__ float lds[50 * 257];
  const int tid = threadIdx.x;
  int blk = blockIdx.x;
  int b = blk / 125, vt = blk % 125;
  int v0 = vt * 256;
  const unsigned short* lb = (const unsigned short*)(out + OUT_ATTN);
  const float* lse = ws + OFF_LSE;
  for (int tt = 0; tt < TOUTS; ++tt) {
    unsigned short us = lb[((size_t)tt * 32 + b) * VOC + v0 + tid];
    lds[tt * 257 + tid] = bf2f(us) - lse[tt * 32 + b];
  }
  __syncthreads();
  float* ob = out + ((size_t)b * VOC + v0) * TOUTS;
  for (int j = 0; j < 50; ++j) {
    int flat = j * 256 + tid;
    int vloc = flat / 50, tt = flat - vloc * 50;
    ob[flat] = lds[tt * 257 + vloc];
  }
}

// ---------------------------------------------------------------- k_fill ---
__global__ void k_fill(float* __restrict__ out) {
  float4* a4 = (float4*)(out + OUT_ATTN);
  unsigned int idx = blockIdx.x * 256 + threadIdx.x;
  float4 one = make_float4(1.f, 1.f, 1.f, 1.f);
  for (size_t i = idx; i < 10240000u; i += (size_t)4096 * 256) a4[i] = one;
}

// ---------------------------------------------------------------- launch ---
extern "C" void kernel_launch(void* const* d_in, const int* in_sizes, int n_in,
                              void* d_out, int out_size, void* d_ws, size_t ws_size,
                              hipStream_t stream) {
  (void)in_sizes; (void)n_in; (void)out_size; (void)ws_size;
  const float* enc    = (const float*)d_in[0];
  const int*   y      = (const int*)  d_in[1];
  const float* emb    = (const float*)d_in[2];
  // d_in[3..6]: W_fc, b_fc, W_fc1, W_fc2 -- dead code (softmax over size-1 axis == 1)
  const float* W_comb = (const float*)d_in[7];
  const float* b_comb = (const float*)d_in[8];
  const float* W_ih   = (const float*)d_in[9];
  const float* W_hh   = (const float*)d_in[10];
  const float* b_ih   = (const float*)d_in[11];
  const float* b_hh   = (const float*)d_in[12];
  const float* W_out  = (const float*)d_in[13];
  const float* b_out  = (const float*)d_in[14];
  float* out = (float*)d_out;
  float* ws  = (float*)d_ws;

  k_setup1<<<64, 256, 0, stream>>>(enc, ws);
  k_setup2<<<64, 256, 0, stream>>>(W_comb, b_comb, ws);
  for (int t = 0; t < TOUTS; ++t) {
    k_xc    <<<64,  256, 0, stream>>>(emb, y, W_comb, ws, t);
    k_gru   <<<256, 256, 0, stream>>>(W_ih, W_hh, b_ih, b_hh, ws, t);
    k_logits<<<NBL, 256, 0, stream>>>(W_out, b_out, ws, out, t);
  }
  k_last     <<<64,   256, 0, stream>>>(ws, out);
  k_transpose<<<4000, 256, 0, stream>>>(ws, out);
  k_fill     <<<4096, 256, 0, stream>>>(out);
}